// Round 23
// baseline (409.955 us; speedup 1.0000x reference)
//
#include <hip/hip_runtime.h>
#include <math.h>

#define BB 4
#define NN 2048
#define DD 64
#define PP 8192
#define NSTRIPE 512
#define VV 32          // packed elements per lane; one wave64 per column-pair
#define GG 16          // projections per block (full MFMA N-width)
#define HROWS 1024     // rows staged per stage (half of NN)

typedef unsigned int u32;
typedef _Float16 h2 __attribute__((ext_vector_type(2)));
typedef __fp16 fh8 __attribute__((ext_vector_type(8)));
typedef float f32x4 __attribute__((ext_vector_type(4)));
typedef u32 u32x4 __attribute__((ext_vector_type(4)));

__global__ void zero_ws_kernel(float* ws) {
    int t = blockIdx.x * blockDim.x + threadIdx.x;
    if (t < BB * NSTRIPE) ws[t] = 0.f;
}

__device__ __forceinline__ u32 pk2u(float a, float b) {
    return __builtin_bit_cast(u32, __builtin_amdgcn_cvt_pkrtz(a, b));
}

// f32 -> fp16 pre-conversion (one pass over x / y)
__global__ __launch_bounds__(256) void cvt_kernel(const float* __restrict__ in,
                                                  u32* __restrict__ out, int n4) {
    int i = blockIdx.x * blockDim.x + threadIdx.x;
    if (i < n4) {
        float4 f = ((const float4*)in)[i];
        uint2 r;
        r.x = pk2u(f.x, f.y);
        r.y = pk2u(f.z, f.w);
        ((uint2*)out)[i] = r;
    }
}

// SINGLE-INSTRUCTION packed fp16 min/max (VOP3P) — r20-verified +18%
__device__ __forceinline__ u32 pk_min(u32 a, u32 b) {
    u32 r;
    asm("v_pk_min_f16 %0, %1, %2" : "=v"(r) : "v"(a), "v"(b));
    return r;
}
__device__ __forceinline__ u32 pk_max(u32 a, u32 b) {
    u32 r;
    asm("v_pk_max_f16 %0, %1, %2" : "=v"(r) : "v"(a), "v"(b));
    return r;
}

__device__ __forceinline__ void ceA(u32& a, u32& b) {
    u32 lo = pk_min(a, b), hi = pk_max(a, b);
    a = lo; b = hi;
}

// lane-xor fetch. DPP (VALU) for free quad_perm masks 1,2,3;
// ds_swizzle (LDS pipe) for 4,7,8,15,16,31; bpermute for 63.
template<int LM>
__device__ __forceinline__ u32 lxf(u32 x, int a63) {
    if constexpr (LM == 1)       return (u32)__builtin_amdgcn_update_dpp((int)x, (int)x, 0xB1, 0xF, 0xF, false);
    else if constexpr (LM == 2)  return (u32)__builtin_amdgcn_update_dpp((int)x, (int)x, 0x4E, 0xF, 0xF, false);
    else if constexpr (LM == 3)  return (u32)__builtin_amdgcn_update_dpp((int)x, (int)x, 0x1B, 0xF, 0xF, false);
    else if constexpr (LM == 63) return (u32)__builtin_amdgcn_ds_bpermute(a63, (int)x);
    else                         return (u32)__builtin_amdgcn_ds_swizzle((int)x, 0x1F | (LM << 10));
}

// ---- Batcher odd-even mergesort of the 32 intra-lane elements (191 comparators)
template<int LO, int N, int R>
__device__ __forceinline__ void oem_merge(u32* e) {
    constexpr int M = R * 2;
    if constexpr (M < N) {
        oem_merge<LO, N, M>(e);
        oem_merge<LO + R, N, M>(e);
        #pragma unroll
        for (int i = LO + R; i + R < LO + N; i += M)
            ceA(e[i], e[i + R]);
    } else {
        ceA(e[LO], e[LO + R]);
    }
}

template<int LO, int N>
__device__ __forceinline__ void oem_sort(u32* e) {
    if constexpr (N > 1) {
        oem_sort<LO, N / 2>(e);
        oem_sort<LO + N / 2, N / 2>(e);
        oem_merge<LO, N, 1>(e);
    }
}

// bitonic cleaner j = 16..1 (static ascending)
__device__ __forceinline__ void clean16(u32* e) {
    #pragma unroll
    for (int j = 16; j >= 1; j >>= 1)
        #pragma unroll
        for (int v = 0; v < VV; v++)
            if ((v & j) == 0) ceA(e[v], e[v | j]);
}

// aligned cross pass: per-element fetch (full exec) + divergent apply
template<int LM>
__device__ __forceinline__ void crossA(u32* e, int lane, int a63) {
    const bool keep = (lane & LM) == 0;
    #pragma unroll
    for (int v = 0; v < VV; v++) {
        u32 p = lxf<LM>(e[v], a63);
        if (keep) e[v] = pk_min(e[v], p);
        else      e[v] = pk_max(e[v], p);
    }
}

template<int LM>
__device__ __forceinline__ void crossA_chain(u32* e, int lane, int a63) {
    crossA<LM>(e, lane, a63);
    if constexpr (LM > 1) crossA_chain<(LM >> 1)>(e, lane, a63);
}

// reflection cross pass: pairwise (v, v^31); both fetches precede both updates
template<int LM>
__device__ __forceinline__ void crossR(u32* e, int lane, bool keep, int a63) {
    #pragma unroll
    for (int v = 0; v < 16; v++) {
        const int w2 = v ^ 31;
        u32 p1 = lxf<LM>(e[w2], a63);
        u32 p2 = lxf<LM>(e[v], a63);
        if (keep) { e[v] = pk_min(e[v], p1); e[w2] = pk_min(e[w2], p2); }
        else      { e[v] = pk_max(e[v], p1); e[w2] = pk_max(e[w2], p2); }
    }
}

template<int K>
__device__ __forceinline__ void level(u32* e, int lane, int a63) {
    crossR<(K >> 5) - 1>(e, lane, (lane & (K >> 6)) == 0, a63);
    if constexpr (K >= 128) crossA_chain<(K >> 7)>(e, lane, a63);
    clean16(e);
}

// LDS half-column swizzle: phys = row ^ ((((row>>5)^g)&7)<<2), row in [0,1024)
__device__ __forceinline__ int swz(int row, int g) {
    return row ^ ((((row >> 5) ^ g) & 7) << 2);
}

template<bool PRE>
__global__ __launch_bounds__(1024) void swd_kernel(const float* __restrict__ x,
                                                   const float* __restrict__ y,
                                                   const u32* __restrict__ xh,
                                                   const u32* __restrict__ yh,
                                                   const float* __restrict__ proj,
                                                   float* __restrict__ ws) {
    __shared__ __align__(16) u32 sbu[GG * HROWS];   // 64 KB: 16 cols x 1024 half-rows

    const int tid = threadIdx.x;
    const int lane = tid & 63;
    const int w = tid >> 6;                    // wave id 0..15
    const int g16 = lane & 15;                 // MFMA n / m lane index
    const int kb = lane >> 4;                  // k-group 0..3
    const int blk = blockIdx.x;
    const int b = blk >> 9;                    // 512 blocks per batch
    const int pbase = (blk & 511) << 4;        // 16 proj rows per block

    // ---- B fragments (proj^T): lane g16 -> proj pbase+g16
    u32x4 bw0, bw1;
    {
        const float4* pr = (const float4*)(proj + (size_t)(pbase + g16) * DD);
        float4 f0 = pr[kb * 2], f1 = pr[kb * 2 + 1];
        bw0[0] = pk2u(f0.x, f0.y); bw0[1] = pk2u(f0.z, f0.w);
        bw0[2] = pk2u(f1.x, f1.y); bw0[3] = pk2u(f1.z, f1.w);
        float4 f2 = pr[8 + kb * 2], f3 = pr[8 + kb * 2 + 1];
        bw1[0] = pk2u(f2.x, f2.y); bw1[1] = pk2u(f2.z, f2.w);
        bw1[2] = pk2u(f3.x, f3.y); bw1[3] = pk2u(f3.z, f3.w);
    }
    const fh8 bf0 = __builtin_bit_cast(fh8, bw0);
    const fh8 bf1 = __builtin_bit_cast(fh8, bw1);

    const float* xb = x + (size_t)b * NN * DD;
    const float* yb = y + (size_t)b * NN * DD;
    const u32* xhb = xh + (size_t)b * NN * (DD / 2);
    const u32* yhb = yh + (size_t)b * NN * (DD / 2);

    auto aloadP = [&](const u32* base, int rowbase, int kk) -> fh8 {
        const u32x4* p = (const u32x4*)(base + ((size_t)(rowbase + g16) << 5) + (kk << 4) + (kb << 2));
        return __builtin_bit_cast(fh8, *p);
    };
    auto aloadF = [&](const float* base, int rowbase, int kk) -> fh8 {
        const float4* ar = (const float4*)(base + (size_t)(rowbase + g16) * DD) + kk * 8 + kb * 2;
        float4 a0 = ar[0], a1 = ar[1];
        u32x4 t;
        t[0] = pk2u(a0.x, a0.y); t[1] = pk2u(a0.z, a0.w);
        t[2] = pk2u(a1.x, a1.y); t[3] = pk2u(a1.z, a1.w);
        return __builtin_bit_cast(fh8, t);
    };

    // ---- one stage of the projection: ALL 16 waves active; wave w covers
    // rows t0 + w*64 .. +63 (4 iterations of 16 rows).
    auto mfma_stage = [&](int t0) {
        #pragma unroll 2
        for (int t2 = 0; t2 < 4; t2++) {
            const int rowbase = t0 + (w << 6) + (t2 << 4);
            f32x4 accx = {0.f, 0.f, 0.f, 0.f};
            f32x4 accy = {0.f, 0.f, 0.f, 0.f};
            if constexpr (PRE) {
                accx = __builtin_amdgcn_mfma_f32_16x16x32_f16(aloadP(xhb, rowbase, 0), bf0, accx, 0, 0, 0);
                accx = __builtin_amdgcn_mfma_f32_16x16x32_f16(aloadP(xhb, rowbase, 1), bf1, accx, 0, 0, 0);
                accy = __builtin_amdgcn_mfma_f32_16x16x32_f16(aloadP(yhb, rowbase, 0), bf0, accy, 0, 0, 0);
                accy = __builtin_amdgcn_mfma_f32_16x16x32_f16(aloadP(yhb, rowbase, 1), bf1, accy, 0, 0, 0);
            } else {
                accx = __builtin_amdgcn_mfma_f32_16x16x32_f16(aloadF(xb, rowbase, 0), bf0, accx, 0, 0, 0);
                accx = __builtin_amdgcn_mfma_f32_16x16x32_f16(aloadF(xb, rowbase, 1), bf1, accx, 0, 0, 0);
                accy = __builtin_amdgcn_mfma_f32_16x16x32_f16(aloadF(yb, rowbase, 0), bf0, accy, 0, 0, 0);
                accy = __builtin_amdgcn_mfma_f32_16x16x32_f16(aloadF(yb, rowbase, 1), bf1, accy, 0, 0, 0);
            }
            // C layout (m89-verified): col g = lane&15, row = rowbase + (lane>>4)*4 + r
            const int R0 = (rowbase + (kb << 2)) & (HROWS - 1);   // half-row index
            u32x4 pk;
            #pragma unroll
            for (int r = 0; r < 4; r++)
                pk[r] = pk2u(accx[r], accy[r]);                    // x -> lo, y -> hi
            *(u32x4*)(sbu + (g16 << 10) + swz(R0, g16)) = pk;      // 16B-aligned
        }
    };

    const int g = w;
    const int xm = (lane ^ g) & 7;             // readback chunk swizzle
    const u32* colb = sbu + (g << 10) + ((lane & 31) << 5);
    u32 e[VV];

    auto readback = [&]() {
        #pragma unroll
        for (int c = 0; c < 8; c++) {          // logical chunk c at phys c^xm
            uint4 tq = *(const uint4*)(colb + ((c ^ xm) << 2));
            e[c * 4 + 0] = tq.x; e[c * 4 + 1] = tq.y;
            e[c * 4 + 2] = tq.z; e[c * 4 + 3] = tq.w;
        }
    };

    mfma_stage(0);                             // stage A: rows 0..1023 (all waves)
    __syncthreads();
    if (lane < 32) readback();                 // lanes<32 own rows 0..1023
    __syncthreads();
    mfma_stage(HROWS);                         // stage B: rows 1024..2047 (all waves)
    __syncthreads();
    if (lane >= 32) readback();                // lanes>=32 own rows 1024..2047

    // ---- sort: wave w sorts column g = w, fully wave-local (no barriers)
    const int a63 = (lane ^ 63) << 2;

    oem_sort<0, VV>(e);                    // Batcher: ascending runs of 32 per lane
    level<64>(e, lane, a63);
    level<128>(e, lane, a63);
    level<256>(e, lane, a63);
    level<512>(e, lane, a63);
    level<1024>(e, lane, a63);
    level<2048>(e, lane, a63);

    // sum of squared diffs: lo = sorted x-col, hi = sorted y-col
    float s = 0.f;
    #pragma unroll
    for (int v = 0; v < VV; v++) {
        h2 h = __builtin_bit_cast(h2, e[v]);
        float d = (float)h[0] - (float)h[1];
        s += d * d;
    }
    #pragma unroll
    for (int off = 32; off > 0; off >>= 1)
        s += __shfl_down(s, off, 64);
    if (lane == 0)
        atomicAdd(&ws[b * NSTRIPE + ((pbase + g) & (NSTRIPE - 1))], s);
}

__global__ void finalize_kernel(const float* __restrict__ ws, float* __restrict__ out) {
    __shared__ float red[256];
    int tid = threadIdx.x;
    for (int b = 0; b < BB; b++) {
        float s = 0.f;
        for (int i = tid; i < NSTRIPE; i += 256) s += ws[b * NSTRIPE + i];
        red[tid] = s;
        __syncthreads();
        for (int o = 128; o > 0; o >>= 1) {
            if (tid < o) red[tid] += red[tid + o];
            __syncthreads();
        }
        if (tid == 0) {
            float swd = red[0] / ((float)NN * (float)PP);
            out[b] = expf(-swd * swd * 0.5f);
        }
        __syncthreads();
    }
}

extern "C" void kernel_launch(void* const* d_in, const int* in_sizes, int n_in,
                              void* d_out, int out_size, void* d_ws, size_t ws_size,
                              hipStream_t stream) {
    const float* x = (const float*)d_in[0];
    const float* y = (const float*)d_in[1];
    const float* proj = (const float*)d_in[2];
    float* out = (float*)d_out;
    float* stripes = (float*)d_ws;
    u32* wsu = (u32*)d_ws;

    const int nhalf = BB * NN * DD;            // 524288 floats per array
    u32* xh = wsu + 4096;                      // fp16 copies at +16 KB
    u32* yh = xh + nhalf / 2;
    const size_t need = 16 * 1024 + (size_t)nhalf * 2 * 2;  // 16 KB + 2 arrays x 1 MB

    zero_ws_kernel<<<(BB * NSTRIPE + 255) / 256, 256, 0, stream>>>(stripes);
    if (ws_size >= need) {
        cvt_kernel<<<(nhalf / 4 + 255) / 256, 256, 0, stream>>>(x, xh, nhalf / 4);
        cvt_kernel<<<(nhalf / 4 + 255) / 256, 256, 0, stream>>>(y, yh, nhalf / 4);
        swd_kernel<true><<<BB * PP / GG, 1024, 0, stream>>>(x, y, xh, yh, proj, stripes);
    } else {
        swd_kernel<false><<<BB * PP / GG, 1024, 0, stream>>>(x, y, xh, yh, proj, stripes);
    }
    finalize_kernel<<<1, 256, 0, stream>>>(stripes, out);
}

// Round 24
// 369.097 us; speedup vs baseline: 1.1107x; 1.1107x over previous
//
#include <hip/hip_runtime.h>
#include <math.h>

#define BB 4
#define NN 2048
#define DD 64
#define PP 8192
#define NSTRIPE 512
#define VV 32          // packed elements per lane; one wave64 per column-pair
#define GG 16          // projections per block (full MFMA N-width)

typedef unsigned int u32;
typedef _Float16 h2 __attribute__((ext_vector_type(2)));
typedef __fp16 fh8 __attribute__((ext_vector_type(8)));
typedef float f32x4 __attribute__((ext_vector_type(4)));
typedef u32 u32x4 __attribute__((ext_vector_type(4)));

__global__ void zero_ws_kernel(float* ws) {
    int t = blockIdx.x * blockDim.x + threadIdx.x;
    if (t < BB * NSTRIPE) ws[t] = 0.f;
}

__device__ __forceinline__ u32 pk2u(float a, float b) {
    return __builtin_bit_cast(u32, __builtin_amdgcn_cvt_pkrtz(a, b));
}

// f32 -> fp16 pre-conversion (one pass over x / y)
__global__ __launch_bounds__(256) void cvt_kernel(const float* __restrict__ in,
                                                  u32* __restrict__ out, int n4) {
    int i = blockIdx.x * blockDim.x + threadIdx.x;
    if (i < n4) {
        float4 f = ((const float4*)in)[i];
        uint2 r;
        r.x = pk2u(f.x, f.y);
        r.y = pk2u(f.z, f.w);
        ((uint2*)out)[i] = r;
    }
}

// SINGLE-INSTRUCTION packed fp16 min/max (VOP3P) — r20-verified +18%
__device__ __forceinline__ u32 pk_min(u32 a, u32 b) {
    u32 r;
    asm("v_pk_min_f16 %0, %1, %2" : "=v"(r) : "v"(a), "v"(b));
    return r;
}
__device__ __forceinline__ u32 pk_max(u32 a, u32 b) {
    u32 r;
    asm("v_pk_max_f16 %0, %1, %2" : "=v"(r) : "v"(a), "v"(b));
    return r;
}

__device__ __forceinline__ void ceA(u32& a, u32& b) {
    u32 lo = pk_min(a, b), hi = pk_max(a, b);
    a = lo; b = hi;
}

// lane-xor fetch. DPP (VALU) only for the free quad_perm masks 1,2,3;
// ds_swizzle (LDS pipe, idle) for 4,7,8,15,16,31; bpermute for 63.
template<int LM>
__device__ __forceinline__ u32 lxf(u32 x, int a63) {
    if constexpr (LM == 1)       return (u32)__builtin_amdgcn_update_dpp((int)x, (int)x, 0xB1, 0xF, 0xF, false);
    else if constexpr (LM == 2)  return (u32)__builtin_amdgcn_update_dpp((int)x, (int)x, 0x4E, 0xF, 0xF, false);
    else if constexpr (LM == 3)  return (u32)__builtin_amdgcn_update_dpp((int)x, (int)x, 0x1B, 0xF, 0xF, false);
    else if constexpr (LM == 63) return (u32)__builtin_amdgcn_ds_bpermute(a63, (int)x);
    else                         return (u32)__builtin_amdgcn_ds_swizzle((int)x, 0x1F | (LM << 10));
}

// ---- Batcher odd-even mergesort of the 32 intra-lane elements (191 comparators
// vs bitonic's 240). Static indices via constexpr recursion; ascending output,
// drop-in compatible with the merge levels below.
template<int LO, int N, int R>
__device__ __forceinline__ void oem_merge(u32* e) {
    constexpr int M = R * 2;
    if constexpr (M < N) {
        oem_merge<LO, N, M>(e);
        oem_merge<LO + R, N, M>(e);
        #pragma unroll
        for (int i = LO + R; i + R < LO + N; i += M)
            ceA(e[i], e[i + R]);
    } else {
        ceA(e[LO], e[LO + R]);
    }
}

template<int LO, int N>
__device__ __forceinline__ void oem_sort(u32* e) {
    if constexpr (N > 1) {
        oem_sort<LO, N / 2>(e);
        oem_sort<LO + N / 2, N / 2>(e);
        oem_merge<LO, N, 1>(e);
    }
}

// bitonic cleaner j = 16..1 (static ascending)
__device__ __forceinline__ void clean16(u32* e) {
    #pragma unroll
    for (int j = 16; j >= 1; j >>= 1)
        #pragma unroll
        for (int v = 0; v < VV; v++)
            if ((v & j) == 0) ceA(e[v], e[v | j]);
}

// divergent keep: fetch ALL partners under full exec, then if/else halves.
__device__ __forceinline__ void apply_keep(u32* e, const u32* p, bool keep) {
    if (keep) {
        #pragma unroll
        for (int v = 0; v < VV; v++) e[v] = pk_min(e[v], p[v]);
    } else {
        #pragma unroll
        for (int v = 0; v < VV; v++) e[v] = pk_max(e[v], p[v]);
    }
}

// aligned cross pass: partner = same elem index at lane^LM
template<int LM>
__device__ __forceinline__ void crossA(u32* e, int lane, int a63) {
    u32 p[VV];
    #pragma unroll
    for (int v = 0; v < VV; v++) p[v] = lxf<LM>(e[v], a63);
    apply_keep(e, p, (lane & LM) == 0);
}

template<int LM>
__device__ __forceinline__ void crossA_chain(u32* e, int lane, int a63) {
    crossA<LM>(e, lane, a63);
    if constexpr (LM > 1) crossA_chain<(LM >> 1)>(e, lane, a63);
}

// reflection cross pass: partner of elem v = elem v^31 at lane^LM
template<int LM>
__device__ __forceinline__ void crossR(u32* e, int lane, bool keep, int a63) {
    u32 p[VV];
    #pragma unroll
    for (int v = 0; v < VV; v++) p[v] = lxf<LM>(e[v ^ 31], a63);
    apply_keep(e, p, keep);
}

template<int K>
__device__ __forceinline__ void level(u32* e, int lane, int a63) {
    crossR<(K >> 5) - 1>(e, lane, (lane & (K >> 6)) == 0, a63);
    if constexpr (K >= 128) crossA_chain<(K >> 7)>(e, lane, a63);
    clean16(e);
}

// LDS column swizzle: phys = row ^ ((((row>>5)^g)&7)<<2)  (bits 2-4; bijective per column)
__device__ __forceinline__ int swz(int row, int g) {
    return row ^ ((((row >> 5) ^ g) & 7) << 2);
}

template<bool PRE>
__global__ __launch_bounds__(1024) void swd_kernel(const float* __restrict__ x,
                                                   const float* __restrict__ y,
                                                   const u32* __restrict__ xh,
                                                   const u32* __restrict__ yh,
                                                   const float* __restrict__ proj,
                                                   float* __restrict__ ws) {
    __shared__ __align__(16) u32 sbu[GG * NN];   // 128 KB: 16 columns of 2048 packed (x,y)

    const int tid = threadIdx.x;
    const int lane = tid & 63;
    const int w = tid >> 6;                    // wave id 0..15
    const int g16 = lane & 15;                 // MFMA n / m lane index
    const int kb = lane >> 4;                  // k-group 0..3
    const int blk = blockIdx.x;
    const int b = blk >> 9;                    // 512 blocks per batch
    const int pbase = (blk & 511) << 4;        // 16 proj rows per block

    // ---- B fragments (proj^T): lane g16 -> proj pbase+g16
    u32x4 bw0, bw1;
    {
        const float4* pr = (const float4*)(proj + (size_t)(pbase + g16) * DD);
        float4 f0 = pr[kb * 2], f1 = pr[kb * 2 + 1];
        bw0[0] = pk2u(f0.x, f0.y); bw0[1] = pk2u(f0.z, f0.w);
        bw0[2] = pk2u(f1.x, f1.y); bw0[3] = pk2u(f1.z, f1.w);
        float4 f2 = pr[8 + kb * 2], f3 = pr[8 + kb * 2 + 1];
        bw1[0] = pk2u(f2.x, f2.y); bw1[1] = pk2u(f2.z, f2.w);
        bw1[2] = pk2u(f3.x, f3.y); bw1[3] = pk2u(f3.z, f3.w);
    }
    const fh8 bf0 = __builtin_bit_cast(fh8, bw0);
    const fh8 bf1 = __builtin_bit_cast(fh8, bw1);

    const float* xb = x + (size_t)b * NN * DD;
    const float* yb = y + (size_t)b * NN * DD;
    const u32* xhb = xh + (size_t)b * NN * (DD / 2);
    const u32* yhb = yh + (size_t)b * NN * (DD / 2);

    auto aloadP = [&](const u32* base, int rowbase, int kk) -> fh8 {
        const u32x4* p = (const u32x4*)(base + ((size_t)(rowbase + g16) << 5) + (kk << 4) + (kb << 2));
        return __builtin_bit_cast(fh8, *p);
    };
    auto aloadF = [&](const float* base, int rowbase, int kk) -> fh8 {
        const float4* ar = (const float4*)(base + (size_t)(rowbase + g16) * DD) + kk * 8 + kb * 2;
        float4 a0 = ar[0], a1 = ar[1];
        u32x4 t;
        t[0] = pk2u(a0.x, a0.y); t[1] = pk2u(a0.z, a0.w);
        t[2] = pk2u(a1.x, a1.y); t[3] = pk2u(a1.z, a1.w);
        return __builtin_bit_cast(fh8, t);
    };

    // ---- projection via MFMA: wave w covers rows w*128 .. +127 of both arrays
    #pragma unroll 2
    for (int t = 0; t < 8; t++) {
        const int rowbase = (w << 7) + (t << 4);
        f32x4 accx = {0.f, 0.f, 0.f, 0.f};
        f32x4 accy = {0.f, 0.f, 0.f, 0.f};
        if constexpr (PRE) {
            accx = __builtin_amdgcn_mfma_f32_16x16x32_f16(aloadP(xhb, rowbase, 0), bf0, accx, 0, 0, 0);
            accx = __builtin_amdgcn_mfma_f32_16x16x32_f16(aloadP(xhb, rowbase, 1), bf1, accx, 0, 0, 0);
            accy = __builtin_amdgcn_mfma_f32_16x16x32_f16(aloadP(yhb, rowbase, 0), bf0, accy, 0, 0, 0);
            accy = __builtin_amdgcn_mfma_f32_16x16x32_f16(aloadP(yhb, rowbase, 1), bf1, accy, 0, 0, 0);
        } else {
            accx = __builtin_amdgcn_mfma_f32_16x16x32_f16(aloadF(xb, rowbase, 0), bf0, accx, 0, 0, 0);
            accx = __builtin_amdgcn_mfma_f32_16x16x32_f16(aloadF(xb, rowbase, 1), bf1, accx, 0, 0, 0);
            accy = __builtin_amdgcn_mfma_f32_16x16x32_f16(aloadF(yb, rowbase, 0), bf0, accy, 0, 0, 0);
            accy = __builtin_amdgcn_mfma_f32_16x16x32_f16(aloadF(yb, rowbase, 1), bf1, accy, 0, 0, 0);
        }
        // C layout (m89-verified): col g = lane&15, row = rowbase + (lane>>4)*4 + r
        const int R0 = rowbase + (kb << 2);                // 4-aligned
        u32x4 pk;
        #pragma unroll
        for (int r = 0; r < 4; r++)
            pk[r] = pk2u(accx[r], accy[r]);                // x -> lo, y -> hi
        *(u32x4*)(sbu + (g16 << 11) + swz(R0, g16)) = pk;  // 16B-aligned (xor bits 2-4)
    }
    __syncthreads();

    // ---- sort: wave w sorts column g = w, fully wave-local (no barriers)
    const int a63 = (lane ^ 63) << 2;
    const int g = w;
    const u32* colbase = sbu + (g << 11) + (lane << 5);
    const int xm = (lane ^ g) & 7;             // readback chunk swizzle

    u32 e[VV];
    #pragma unroll
    for (int c = 0; c < 8; c++) {              // logical chunk c at phys c^xm
        uint4 tq = *(const uint4*)(colbase + ((c ^ xm) << 2));
        e[c * 4 + 0] = tq.x; e[c * 4 + 1] = tq.y;
        e[c * 4 + 2] = tq.z; e[c * 4 + 3] = tq.w;
    }

    oem_sort<0, VV>(e);                    // Batcher: ascending runs of 32 per lane
    level<64>(e, lane, a63);
    level<128>(e, lane, a63);
    level<256>(e, lane, a63);
    level<512>(e, lane, a63);
    level<1024>(e, lane, a63);
    level<2048>(e, lane, a63);

    // sum of squared diffs: lo = sorted x-col, hi = sorted y-col
    float s = 0.f;
    #pragma unroll
    for (int v = 0; v < VV; v++) {
        h2 h = __builtin_bit_cast(h2, e[v]);
        float d = (float)h[0] - (float)h[1];
        s += d * d;
    }
    #pragma unroll
    for (int off = 32; off > 0; off >>= 1)
        s += __shfl_down(s, off, 64);
    if (lane == 0)
        atomicAdd(&ws[b * NSTRIPE + ((pbase + g) & (NSTRIPE - 1))], s);
}

__global__ void finalize_kernel(const float* __restrict__ ws, float* __restrict__ out) {
    __shared__ float red[256];
    int tid = threadIdx.x;
    for (int b = 0; b < BB; b++) {
        float s = 0.f;
        for (int i = tid; i < NSTRIPE; i += 256) s += ws[b * NSTRIPE + i];
        red[tid] = s;
        __syncthreads();
        for (int o = 128; o > 0; o >>= 1) {
            if (tid < o) red[tid] += red[tid + o];
            __syncthreads();
        }
        if (tid == 0) {
            float swd = red[0] / ((float)NN * (float)PP);
            out[b] = expf(-swd * swd * 0.5f);
        }
        __syncthreads();
    }
}

extern "C" void kernel_launch(void* const* d_in, const int* in_sizes, int n_in,
                              void* d_out, int out_size, void* d_ws, size_t ws_size,
                              hipStream_t stream) {
    const float* x = (const float*)d_in[0];
    const float* y = (const float*)d_in[1];
    const float* proj = (const float*)d_in[2];
    float* out = (float*)d_out;
    float* stripes = (float*)d_ws;
    u32* wsu = (u32*)d_ws;

    const int nhalf = BB * NN * DD;            // 524288 floats per array
    u32* xh = wsu + 4096;                      // fp16 copies at +16 KB
    u32* yh = xh + nhalf / 2;
    const size_t need = 16 * 1024 + (size_t)nhalf * 2 * 2;  // 16 KB + 2 arrays x 1 MB

    zero_ws_kernel<<<(BB * NSTRIPE + 255) / 256, 256, 0, stream>>>(stripes);
    if (ws_size >= need) {
        cvt_kernel<<<(nhalf / 4 + 255) / 256, 256, 0, stream>>>(x, xh, nhalf / 4);
        cvt_kernel<<<(nhalf / 4 + 255) / 256, 256, 0, stream>>>(y, yh, nhalf / 4);
        swd_kernel<true><<<BB * PP / GG, 1024, 0, stream>>>(x, y, xh, yh, proj, stripes);
    } else {
        swd_kernel<false><<<BB * PP / GG, 1024, 0, stream>>>(x, y, xh, yh, proj, stripes);
    }
    finalize_kernel<<<1, 256, 0, stream>>>(stripes, out);
}